// Round 4
// 824.054 us; speedup vs baseline: 1.1565x; 1.1565x over previous
//
#include <hip/hip_runtime.h>
#include <cstdint>

#define T_TOK 1024
#define HID   2048
#define INTER 1024
#define NEXP  32
#define NTOT  40
#define RSF   1.0f

typedef short bf16x8 __attribute__((ext_vector_type(8)));
typedef float f32x4  __attribute__((ext_vector_type(4)));

__device__ inline short f2bf(float f) {
    unsigned x = __builtin_bit_cast(unsigned, f);
    x += 0x7fffu + ((x >> 16) & 1u);           // round-to-nearest-even
    return (short)(x >> 16);
}

// ---------------- Kernel 0: hs fp32 -> bf16 (once; 4MB, L2-resident) ----------------
__global__ __launch_bounds__(256) void k_cvt_hs(const float* __restrict__ hs,
                                                unsigned short* __restrict__ hsb)
{
    int idx = blockIdx.x * 256 + threadIdx.x;          // 8 floats per thread
    const float4* s = (const float4*)hs + (size_t)idx * 2;
    float4 a = s[0], b = s[1];
    union { unsigned short u[8]; int4 v; } r;
    r.u[0] = (unsigned short)f2bf(a.x); r.u[1] = (unsigned short)f2bf(a.y);
    r.u[2] = (unsigned short)f2bf(a.z); r.u[3] = (unsigned short)f2bf(a.w);
    r.u[4] = (unsigned short)f2bf(b.x); r.u[5] = (unsigned short)f2bf(b.y);
    r.u[6] = (unsigned short)f2bf(b.z); r.u[7] = (unsigned short)f2bf(b.w);
    ((int4*)hsb)[idx] = r.v;
}

// ---------------- Kernel 1: router (fp32 exact, coalesced float4) ----------------
__global__ __launch_bounds__(256) void k_router(
    const float* __restrict__ hs, const float* __restrict__ rw,
    const float* __restrict__ cb, int* __restrict__ topk_ids,
    float* __restrict__ topk_w, float* __restrict__ zero_w,
    int* __restrict__ counts)
{
    int t = blockIdx.x;
    __shared__ float4 hrow[HID / 4];
    __shared__ float sc[NTOT];
    const float4* h4 = (const float4*)(hs + (size_t)t * HID);
    for (int i = threadIdx.x; i < HID / 4; i += 256) hrow[i] = h4[i];
    __syncthreads();
    int wid = threadIdx.x >> 6, lane = threadIdx.x & 63;
    for (int e = wid; e < NTOT; e += 4) {
        const float4* w4 = (const float4*)(rw + (size_t)e * HID);
        float p = 0.f;
        for (int c = lane; c < HID / 4; c += 64) {
            float4 a = w4[c], b = hrow[c];
            p += a.x * b.x + a.y * b.y + a.z * b.z + a.w * b.w;
        }
        for (int s = 32; s; s >>= 1) p += __shfl_down(p, s, 64);
        if (lane == 0) sc[e] = 1.f / (1.f + expf(-p));
    }
    __syncthreads();
    if (threadIdx.x == 0) {
        float key[NTOT];
        for (int e = 0; e < NTOT; e++) key[e] = sc[e] + cb[e];
        float zw = 0.f;
        for (int k = 0; k < 4; k++) {
            int best = 0; float bv = key[0];
            for (int e = 1; e < NTOT; e++)
                if (key[e] > bv) { bv = key[e]; best = e; }
            key[best] = -1e30f;
            topk_ids[t * 4 + k] = best;
            float wv = sc[best];
            topk_w[t * 4 + k] = wv;
            if (best >= NEXP) zw += wv;
            else atomicAdd(&counts[best], 1);
        }
        zero_w[t] = zw * RSF;
    }
}

// ---------------- Kernel 2: exact prefix (no padding) ----------------
__global__ void k_prefix(const int* __restrict__ counts, int* __restrict__ offsets)
{
    if (threadIdx.x == 0 && blockIdx.x == 0) {
        int acc = 0;
        for (int e = 0; e < NEXP; e++) { offsets[e] = acc; acc += counts[e]; }
        offsets[NEXP] = acc;
    }
}

// ---------------- Kernel 3: scatter into buckets ----------------
__global__ void k_scatter(const int* __restrict__ topk_ids, const float* __restrict__ topk_w,
                          const int* __restrict__ offsets, int* __restrict__ cnt2,
                          int* __restrict__ btok, float* __restrict__ bw)
{
    int t = blockIdx.x * 256 + threadIdx.x;
    if (t >= T_TOK) return;
    for (int k = 0; k < 4; k++) {
        int e = topk_ids[t * 4 + k];
        if (e < NEXP) {
            int pos  = atomicAdd(&cnt2[e], 1);
            int slot = offsets[e] + pos;
            btok[slot] = t;
            bw[slot]   = topk_w[t * 4 + k];
        }
    }
}

// LDS tile: [128 rows][32 shorts]; 16B segment index XOR-swizzled by (row&3)
// on BOTH write and read (involution: read quad q hits stored seg q).
#define SWZ(row, seg) (((row) * 32) + (((seg) ^ ((row) & 3)) * 8))

// ---------------- Kernel 4: grouped GEMM1 + silu -> Hbuf (bf16) ----------------
// 2-phase pipelined dbuf; A bf16 + B fp32 reg-staged (issue-early/write-late);
// B rows interleaved (2i=gate_i, 2i+1=up_i) -> SiLU via shfl_xor, no LDS epilogue.
// grid: x = INTER/64 (16), y = expert (32), z = m-tile (8, early-exit)
__global__ __launch_bounds__(256, 4) void k_ffn1(
    const unsigned short* __restrict__ hsb, const float* __restrict__ w1g,
    const float* __restrict__ w1u, const int* __restrict__ counts,
    const int* __restrict__ offsets, const int* __restrict__ btok,
    unsigned short* __restrict__ Hbuf)
{
    int it = blockIdx.x, e = blockIdx.y, mt = blockIdx.z;
    int ne = counts[e];
    if (mt * 128 >= ne) return;
    int base  = offsets[e] + mt * 128;
    int valid = ne - mt * 128; if (valid > 128) valid = 128;

    __shared__ __align__(16) short At[2][128 * 32];
    __shared__ __align__(16) short Bt[2][128 * 32];
    __shared__ int tok[128];

    int tid = threadIdx.x;
    if (tid < 128) tok[tid] = (tid < valid) ? btok[base + tid] : btok[base];
    __syncthreads();

    // A staging: thread covers 2 segments (16B each): idx = tid + u*256
    const unsigned short* asrc[2]; int adst[2];
#pragma unroll
    for (int u = 0; u < 2; u++) {
        int idx = tid + u * 256;
        int r = idx >> 2, s = idx & 3;
        asrc[u] = hsb + (size_t)tok[r] * HID + s * 8;
        adst[u] = SWZ(r, s);
    }

    // B staging: thread -> LDS row br_ (interleaved gate/up), 16 floats (2 segments)
    // FIX (round 3 bug): expert offset e*INTER*HID was missing -> all experts used e=0 weights.
    int br_ = tid >> 1, half = tid & 1;
    const float* bsrc = ((br_ & 1) ? w1u : w1g)
                      + (size_t)e * INTER * HID
                      + (size_t)(it * 64 + (br_ >> 1)) * HID + half * 16;
    int bdst0 = SWZ(br_, half * 2);
    int bdst1 = SWZ(br_, half * 2 + 1);

    f32x4 acc[4][4];
#pragma unroll
    for (int mi = 0; mi < 4; mi++)
#pragma unroll
        for (int ni = 0; ni < 4; ni++) acc[mi][ni] = 0.f;

    int wid = tid >> 6, lane = tid & 63;
    int wrow = (wid >> 1) * 64, wcol = (wid & 1) * 64;
    int lrow = lane & 15, quad = lane >> 4;

    int4  an[2];
    float4 bn[4];
    // prologue: fetch + publish K-tile 0 into buffer 0
#pragma unroll
    for (int u = 0; u < 2; u++) an[u] = *(const int4*)asrc[u];
#pragma unroll
    for (int u = 0; u < 4; u++) bn[u] = *(const float4*)(bsrc + u * 4);
#pragma unroll
    for (int u = 0; u < 2; u++) *(int4*)&At[0][adst[u]] = an[u];
    {
        union { short s[8]; int4 v; } p0, p1;
        p0.s[0]=f2bf(bn[0].x); p0.s[1]=f2bf(bn[0].y); p0.s[2]=f2bf(bn[0].z); p0.s[3]=f2bf(bn[0].w);
        p0.s[4]=f2bf(bn[1].x); p0.s[5]=f2bf(bn[1].y); p0.s[6]=f2bf(bn[1].z); p0.s[7]=f2bf(bn[1].w);
        p1.s[0]=f2bf(bn[2].x); p1.s[1]=f2bf(bn[2].y); p1.s[2]=f2bf(bn[2].z); p1.s[3]=f2bf(bn[2].w);
        p1.s[4]=f2bf(bn[3].x); p1.s[5]=f2bf(bn[3].y); p1.s[6]=f2bf(bn[3].z); p1.s[7]=f2bf(bn[3].w);
        *(int4*)&Bt[0][bdst0] = p0.v;
        *(int4*)&Bt[0][bdst1] = p1.v;
    }
    __syncthreads();

    int cur = 0;
    for (int kt = 0; kt < HID / 32; kt++) {
        bool pf = (kt < HID / 32 - 1);
        if (pf) {                                   // issue next-tile loads FIRST
            int k0n = (kt + 1) * 32;
#pragma unroll
            for (int u = 0; u < 2; u++) an[u] = *(const int4*)(asrc[u] + k0n);
#pragma unroll
            for (int u = 0; u < 4; u++) bn[u] = *(const float4*)(bsrc + k0n + u * 4);
        }
        // MFMA phase on buf[cur] (HBM latency of an/bn hides under this)
        bf16x8 bfr[4];
#pragma unroll
        for (int ni = 0; ni < 4; ni++) {
            int rb = wcol + ni * 16 + lrow;
            bfr[ni] = *(bf16x8*)&Bt[cur][SWZ(rb, quad)];
        }
#pragma unroll
        for (int mi = 0; mi < 4; mi++) {
            int ra = wrow + mi * 16 + lrow;
            bf16x8 af = *(bf16x8*)&At[cur][SWZ(ra, quad)];
#pragma unroll
            for (int ni = 0; ni < 4; ni++)
                acc[mi][ni] = __builtin_amdgcn_mfma_f32_16x16x32_bf16(af, bfr[ni], acc[mi][ni], 0, 0, 0);
        }
        if (pf) {                                   // publish next tile (write-late)
#pragma unroll
            for (int u = 0; u < 2; u++) *(int4*)&At[cur ^ 1][adst[u]] = an[u];
            union { short s[8]; int4 v; } p0, p1;
            p0.s[0]=f2bf(bn[0].x); p0.s[1]=f2bf(bn[0].y); p0.s[2]=f2bf(bn[0].z); p0.s[3]=f2bf(bn[0].w);
            p0.s[4]=f2bf(bn[1].x); p0.s[5]=f2bf(bn[1].y); p0.s[6]=f2bf(bn[1].z); p0.s[7]=f2bf(bn[1].w);
            p1.s[0]=f2bf(bn[2].x); p1.s[1]=f2bf(bn[2].y); p1.s[2]=f2bf(bn[2].z); p1.s[3]=f2bf(bn[2].w);
            p1.s[4]=f2bf(bn[3].x); p1.s[5]=f2bf(bn[3].y); p1.s[6]=f2bf(bn[3].z); p1.s[7]=f2bf(bn[3].w);
            *(int4*)&Bt[cur ^ 1][bdst0] = p0.v;
            *(int4*)&Bt[cur ^ 1][bdst1] = p1.v;
        }
        __syncthreads();
        cur ^= 1;
    }

    // epilogue: adjacent lanes hold (gate, up) for same i -> shfl_xor pairwise SiLU
#pragma unroll
    for (int mi = 0; mi < 4; mi++) {
#pragma unroll
        for (int ni = 0; ni < 4; ni++) {
#pragma unroll
            for (int rr = 0; rr < 4; rr++) {
                float v = acc[mi][ni][rr];
                float o = __shfl_xor(v, 1, 64);
                int m = wrow + mi * 16 + quad * 4 + rr;
                if (!(lrow & 1) && m < valid) {
                    float g = v;
                    float h = g / (1.f + __expf(-g)) * o;
                    int col = wcol + ni * 16 + lrow;   // even
                    Hbuf[(size_t)(base + m) * INTER + it * 64 + (col >> 1)] =
                        (unsigned short)f2bf(h);
                }
            }
        }
    }
}

// ---------------- Kernel 5: out = hidden * zero_weight ----------------
__global__ void k_init_out(const float* __restrict__ hs, const float* __restrict__ zw,
                           float* __restrict__ out)
{
    int idx = blockIdx.x * 256 + threadIdx.x;   // float4 index
    int t = idx >> 9;                           // HID/4 = 512 per row
    float4 v = ((const float4*)hs)[idx];
    float s = zw[t];
    v.x *= s; v.y *= s; v.z *= s; v.w *= s;
    ((float4*)out)[idx] = v;
}

// ---------------- Kernel 6: grouped GEMM2, weighted atomic accumulate ----------------
// same 2-phase pipeline; A = Hbuf bf16, B = w2 fp32, both reg-staged + swizzled LDS.
// grid: x = H/128 (16), y = expert (32), z = m-tile (8)
__global__ __launch_bounds__(256, 4) void k_ffn2(
    const unsigned short* __restrict__ Hbuf, const float* __restrict__ w2,
    const int* __restrict__ counts, const int* __restrict__ offsets,
    const int* __restrict__ btok, const float* __restrict__ bw,
    float* __restrict__ out)
{
    int ht = blockIdx.x, e = blockIdx.y, mt = blockIdx.z;
    int ne = counts[e];
    if (mt * 128 >= ne) return;
    int base  = offsets[e] + mt * 128;
    int valid = ne - mt * 128; if (valid > 128) valid = 128;

    __shared__ __align__(16) short At[2][128 * 32];
    __shared__ __align__(16) short Bt[2][128 * 32];
    __shared__ int   tok[128];
    __shared__ float wgt[128];

    int tid = threadIdx.x;
    if (tid < 128) {
        tok[tid] = (tid < valid) ? btok[base + tid] : 0;
        wgt[tid] = (tid < valid) ? bw[base + tid] * RSF : 0.f;
    }
    __syncthreads();

    const unsigned short* asrc[2]; int adst[2];
#pragma unroll
    for (int u = 0; u < 2; u++) {
        int idx = tid + u * 256;
        int r = idx >> 2, s = idx & 3;
        asrc[u] = Hbuf + (size_t)(base + r) * INTER + s * 8;
        adst[u] = SWZ(r, s);
    }

    int br_ = tid >> 1, half = tid & 1;
    const float* bsrc = w2 + (size_t)e * HID * INTER
                      + (size_t)(ht * 128 + br_) * INTER + half * 16;
    int bdst0 = SWZ(br_, half * 2);
    int bdst1 = SWZ(br_, half * 2 + 1);

    f32x4 acc[4][4];
#pragma unroll
    for (int mi = 0; mi < 4; mi++)
#pragma unroll
        for (int ni = 0; ni < 4; ni++) acc[mi][ni] = 0.f;

    int wid = tid >> 6, lane = tid & 63;
    int wrow = (wid >> 1) * 64, wcol = (wid & 1) * 64;
    int lrow = lane & 15, quad = lane >> 4;

    int4  an[2];
    float4 bn[4];
#pragma unroll
    for (int u = 0; u < 2; u++) an[u] = *(const int4*)asrc[u];
#pragma unroll
    for (int u = 0; u < 4; u++) bn[u] = *(const float4*)(bsrc + u * 4);
#pragma unroll
    for (int u = 0; u < 2; u++) *(int4*)&At[0][adst[u]] = an[u];
    {
        union { short s[8]; int4 v; } p0, p1;
        p0.s[0]=f2bf(bn[0].x); p0.s[1]=f2bf(bn[0].y); p0.s[2]=f2bf(bn[0].z); p0.s[3]=f2bf(bn[0].w);
        p0.s[4]=f2bf(bn[1].x); p0.s[5]=f2bf(bn[1].y); p0.s[6]=f2bf(bn[1].z); p0.s[7]=f2bf(bn[1].w);
        p1.s[0]=f2bf(bn[2].x); p1.s[1]=f2bf(bn[2].y); p1.s[2]=f2bf(bn[2].z); p1.s[3]=f2bf(bn[2].w);
        p1.s[4]=f2bf(bn[3].x); p1.s[5]=f2bf(bn[3].y); p1.s[6]=f2bf(bn[3].z); p1.s[7]=f2bf(bn[3].w);
        *(int4*)&Bt[0][bdst0] = p0.v;
        *(int4*)&Bt[0][bdst1] = p1.v;
    }
    __syncthreads();

    int cur = 0;
    for (int kt = 0; kt < INTER / 32; kt++) {
        bool pf = (kt < INTER / 32 - 1);
        if (pf) {
            int k0n = (kt + 1) * 32;
#pragma unroll
            for (int u = 0; u < 2; u++) an[u] = *(const int4*)(asrc[u] + k0n);
#pragma unroll
            for (int u = 0; u < 4; u++) bn[u] = *(const float4*)(bsrc + k0n + u * 4);
        }
        bf16x8 bfr[4];
#pragma unroll
        for (int ni = 0; ni < 4; ni++) {
            int rb = wcol + ni * 16 + lrow;
            bfr[ni] = *(bf16x8*)&Bt[cur][SWZ(rb, quad)];
        }
#pragma unroll
        for (int mi = 0; mi < 4; mi++) {
            int ra = wrow + mi * 16 + lrow;
            bf16x8 af = *(bf16x8*)&At[cur][SWZ(ra, quad)];
#pragma unroll
            for (int ni = 0; ni < 4; ni++)
                acc[mi][ni] = __builtin_amdgcn_mfma_f32_16x16x32_bf16(af, bfr[ni], acc[mi][ni], 0, 0, 0);
        }
        if (pf) {
#pragma unroll
            for (int u = 0; u < 2; u++) *(int4*)&At[cur ^ 1][adst[u]] = an[u];
            union { short s[8]; int4 v; } p0, p1;
            p0.s[0]=f2bf(bn[0].x); p0.s[1]=f2bf(bn[0].y); p0.s[2]=f2bf(bn[0].z); p0.s[3]=f2bf(bn[0].w);
            p0.s[4]=f2bf(bn[1].x); p0.s[5]=f2bf(bn[1].y); p0.s[6]=f2bf(bn[1].z); p0.s[7]=f2bf(bn[1].w);
            p1.s[0]=f2bf(bn[2].x); p1.s[1]=f2bf(bn[2].y); p1.s[2]=f2bf(bn[2].z); p1.s[3]=f2bf(bn[2].w);
            p1.s[4]=f2bf(bn[3].x); p1.s[5]=f2bf(bn[3].y); p1.s[6]=f2bf(bn[3].z); p1.s[7]=f2bf(bn[3].w);
            *(int4*)&Bt[cur ^ 1][bdst0] = p0.v;
            *(int4*)&Bt[cur ^ 1][bdst1] = p1.v;
        }
        __syncthreads();
        cur ^= 1;
    }

    // epilogue: weighted atomic accumulate into out (fp32)
#pragma unroll
    for (int mi = 0; mi < 4; mi++) {
#pragma unroll
        for (int rr = 0; rr < 4; rr++) {
            int m = wrow + mi * 16 + quad * 4 + rr;
            if (m < valid) {
                int   t = tok[m];
                float w = wgt[m];
                float* orow = out + (size_t)t * HID + ht * 128;
#pragma unroll
                for (int ni = 0; ni < 4; ni++)
                    atomicAdd(&orow[wcol + ni * 16 + lrow], acc[mi][ni][rr] * w);
            }
        }
    }
}

extern "C" void kernel_launch(void* const* d_in, const int* in_sizes, int n_in,
                              void* d_out, int out_size, void* d_ws, size_t ws_size,
                              hipStream_t stream)
{
    const float* hs  = (const float*)d_in[0];
    const float* rw  = (const float*)d_in[1];
    const float* cb  = (const float*)d_in[2];
    const float* w1g = (const float*)d_in[3];
    const float* w1u = (const float*)d_in[4];
    const float* w2  = (const float*)d_in[5];
    float* out = (float*)d_out;

    char* ws = (char*)d_ws;
    int*   counts   = (int*)(ws + 0);        // 32
    int*   cnt2     = (int*)(ws + 128);      // 32
    int*   offsets  = (int*)(ws + 256);      // 33
    int*   topk_ids = (int*)(ws + 4096);     // 1024*4
    float* topk_w   = (float*)(ws + 20480);  // 1024*4
    float* zero_w   = (float*)(ws + 36864);  // 1024
    int*   btok     = (int*)(ws + 40960);    // 4096 slots (exact, no padding)
    float* bww      = (float*)(ws + 73728);  // 4096
    unsigned short* hsb  = (unsigned short*)(ws + 131072);                       // 4 MB bf16 hs
    unsigned short* Hbuf = (unsigned short*)(ws + 131072 + (size_t)T_TOK * HID * 2); // 4224 rows x 1024 bf16 (~8.65MB incl. slack)

    hipMemsetAsync(d_ws, 0, 4096, stream);   // counts/cnt2/offsets

    k_cvt_hs<<<T_TOK * HID / 8 / 256, 256, 0, stream>>>(hs, hsb);
    k_router<<<T_TOK, 256, 0, stream>>>(hs, rw, cb, topk_ids, topk_w, zero_w, counts);
    k_prefix<<<1, 64, 0, stream>>>(counts, offsets);
    k_scatter<<<4, 256, 0, stream>>>(topk_ids, topk_w, offsets, cnt2, btok, bww);
    k_ffn1<<<dim3(16, 32, 8), 256, 0, stream>>>(hsb, w1g, w1u, counts, offsets, btok, Hbuf);
    k_init_out<<<(T_TOK * HID / 4) / 256, 256, 0, stream>>>(hs, zero_w, out);
    k_ffn2<<<dim3(16, 32, 8), 256, 0, stream>>>(Hbuf, w2, counts, offsets, btok, bww, out);
}